// Round 13
// baseline (207.111 us; speedup 1.0000x reference)
//
#include <hip/hip_runtime.h>
#include <hip/hip_bf16.h>

typedef __attribute__((ext_vector_type(8))) short short8;
typedef __attribute__((ext_vector_type(4))) float f32x4;
typedef __attribute__((ext_vector_type(2))) unsigned int uint2v;

#define PATH_W 0.0625f
#define INV_SQRT3 0.57735026918962576f

typedef const __attribute__((address_space(1))) char gchar;
typedef __attribute__((address_space(3))) char schar;

__device__ __forceinline__ unsigned short f2bf(float f) {
    unsigned int u = __builtin_bit_cast(unsigned int, f);
    u += 0x7FFFu + ((u >> 16) & 1u);   // round-to-nearest-even
    return (unsigned short)(u >> 16);
}

__device__ __forceinline__ float silu(float x) {
    return x / (1.0f + __expf(-x));
}

// ---------------------------------------------------------------------------
// Prep: block 0 -> coefficient/constant table (pre-scaled coeffs + biases).
// Blocks 1..128 -> frag-major bf16 weight fragments:
//   W1 (fid 0..63)  STANDARD pack: k = ks*32 + g*8 + half*4 + j
//   W2 (fid 64..95) STANDARD pack (B-frags now come from h1 memory in
//                   standard layout, so A must match)
//   W3 (fid 96..127) PHI pack: k = half*64 + ks*16 + g*4 + j  (matches the
//                   GEMM2 D-register layout -> in-register repack, no xchg)
// ---------------------------------------------------------------------------
__global__ void prep_all(const float* __restrict__ Wq0, const float* __restrict__ bq,
                         const float* __restrict__ Wv0, const float* __restrict__ bv,
                         const float* __restrict__ Wv1, const float* __restrict__ wq_s,
                         const float* __restrict__ wv_s, const float* __restrict__ wv_v,
                         const float* __restrict__ W1, const float* __restrict__ W2,
                         const float* __restrict__ W3, const float* __restrict__ b1,
                         const float* __restrict__ b2, const float* __restrict__ b3,
                         const float* __restrict__ W4, const float* __restrict__ b4,
                         float* __restrict__ vecs, unsigned short* __restrict__ wp) {
    if (blockIdx.x == 0) {
        int u = threadIdx.x;  // 0..127
        float aq = 0.f, bqs = 0.f, av = 0.f, bvs = 0.f, a1 = 0.f;
        for (int v = 0; v < 128; ++v) {
            float rq = wq_s[u * 128 + v];
            float rv = wv_s[u * 128 + v];
            aq  += Wq0[v] * rq;
            bqs += bq[v]  * rq;
            av  += Wv0[v] * rv;
            bvs += bv[v]  * rv;
            a1  += Wv1[v] * wv_v[u * 128 + v];
        }
        vecs[u]        = PATH_W * aq;
        vecs[128 + u]  = PATH_W * bqs;
        vecs[256 + u]  = PATH_W * av;
        vecs[384 + u]  = PATH_W * bvs;
        vecs[512 + u]  = PATH_W * INV_SQRT3 * a1;
        vecs[640 + u]  = b1[u];
        vecs[768 + u]  = b2[u];
        vecs[896 + u]  = b3[u];
        vecs[1024 + u] = W4[u];
        if (u == 0) { vecs[1152] = b4[0]; vecs[1153] = 0.f; vecs[1154] = 0.f; vecs[1155] = 0.f; }
        return;
    }
    int fid  = blockIdx.x - 1;      // 0..127
    int t    = threadIdx.x;         // 0..127
    int lane = t & 63;
    int half = t >> 6;
    int g  = lane >> 4;
    int r  = lane & 15;
    const float* W;
    int row0, col;
    if (fid < 64) {                       // W1: standard pack
        int mt = fid >> 3, ks = fid & 7;
        W = W1; col = mt * 16 + r;
        row0 = ks * 32 + g * 8 + half * 4;
    } else if (fid < 96) {                // W2: standard pack
        int f2 = fid - 64;
        int mt = f2 >> 2, ks = f2 & 3;
        W = W2; col = mt * 16 + r;
        row0 = ks * 32 + g * 8 + half * 4;
    } else {                              // W3: phi pack
        int f2 = fid - 96;
        int mt = f2 >> 2, ks = f2 & 3;
        W = W3; col = mt * 16 + r;
        row0 = half * 64 + ks * 16 + g * 4;
    }
    unsigned short* dst = wp + fid * 512 + lane * 8 + half * 4;
    #pragma unroll
    for (int j = 0; j < 4; ++j) dst[j] = f2bf(W[(row0 + j) * 128 + col]);
}

// ---------------------------------------------------------------------------
// Kernel A: gather + h-compute + GEMM1 + silu -> h1 (bf16, [n][128] = 256B/row)
// 256 threads = 4 waves; LDS = W1 (64KB) + consts -> TWO blocks/CU, de-phased.
// (256,1) -> 256-VGPR cap: r8's proven full-tile register prefetch (~232
// live, no spill) with two bursts bracketing GEMM1. No GEMM2/3 tail, so the
// vmem pipe stays fed nearly the whole tile.
// ---------------------------------------------------------------------------
__global__ __launch_bounds__(256, 1) void gemm1_fused(
    const float* __restrict__ nf,     // node_feats [N,512]
    const float* __restrict__ field,  // field_feats [N,4]
    const float* __restrict__ c0, const float* __restrict__ ci,
    const float* __restrict__ vecs,   // constant table (1156 f32)
    const unsigned short* __restrict__ wp,
    unsigned short* __restrict__ h1,  // out: [N][128] bf16
    int N)
{
    __shared__ __align__(16) char smem[65536];
    __shared__ __align__(16) float vlds[1156];
    const int tid  = threadIdx.x;
    const int wave = tid >> 6;      // 0..3
    const int lane = tid & 63;
    const int g    = lane >> 4;
    const int nl   = lane & 15;
    const int T    = (N + 63) >> 6;
    const char* wpb = (const char*)wp;

    // ---- stage W1 (64KB) into LDS once (16KB per wave) ----
    #pragma unroll
    for (int i = 0; i < 16; ++i) {
        int off = (wave * 16 + i) * 1024;
        __builtin_amdgcn_global_load_lds((gchar*)(wpb + off + lane * 16),
                                         (schar*)(smem + off), 16, 0, 0);
    }
    if (wave == 0) {
        #pragma unroll
        for (int i = 0; i < 5; ++i) {
            int idx = lane + 64 * i;
            if (idx < 289)
                reinterpret_cast<f32x4*>(vlds)[idx] =
                    reinterpret_cast<const f32x4*>(vecs)[idx];
        }
    }

    // full-tile node buffer: 8 half-quarters x (s 16B + v 48B) = 512B/lane
    f32x4 hs[8], hv0[8], hv1[8], hv2[8];
    float c0r, cir; f32x4 ffr;

#define NLOAD_RANGE(ndx, H0, H1) {                                            \
        const char* nrow_ = (const char*)nf + (size_t)(ndx) * 2048;           \
        _Pragma("unroll")                                                     \
        for (int hh_ = (H0); hh_ < (H1); ++hh_) {                             \
            const int k_ = hh_ >> 1, h_ = hh_ & 1;                            \
            const char* p_ = nrow_ + 512 + 384 * k_ + 96 * g + 48 * h_;       \
            hs[hh_]  = *reinterpret_cast<const f32x4*>(nrow_ + 128 * k_ + 32 * g + 16 * h_); \
            hv0[hh_] = *reinterpret_cast<const f32x4*>(p_);                   \
            hv1[hh_] = *reinterpret_cast<const f32x4*>(p_ + 16);              \
            hv2[hh_] = *reinterpret_cast<const f32x4*>(p_ + 32);              \
        } }
#define NLOAD_SC(ndx) {                                                       \
        c0r = c0[ndx]; cir = ci[ndx];                                         \
        ffr = reinterpret_cast<const f32x4*>(field)[ndx]; }

    int tile = blockIdx.x;
    {   // prologue: full tile 0
        int nd0 = tile * 64 + wave * 16 + nl;
        int ndc = nd0 < N ? nd0 : N - 1;
        NLOAD_RANGE(ndc, 0, 8)
        NLOAD_SC(ndc)
    }

    __syncthreads();   // W1 + consts resident

    const f32x4* vl4 = reinterpret_cast<const f32x4*>(vlds);

    for (; tile < T; tile += gridDim.x) {
        const int nd = tile * 64 + wave * 16 + nl;
        const float q_in = c0r + cir;
        const f32x4 ff   = ffr;

        // ---- h-fragment compute (consumes buffer) ----
        short8 hfrag[8];
        #pragma unroll
        for (int hh = 0; hh < 8; ++hh) {
            const int k = hh >> 1, h = hh & 1;
            const int m = 8 * k + 2 * g + h;
            f32x4 aq = vl4[m], bqv = vl4[32 + m], av = vl4[64 + m],
                  bvv = vl4[96 + m], a1 = vl4[128 + m];
            f32x4 s = hs[hh], va = hv0[hh], vb = hv1[hh], vc = hv2[hh];
            float d3[4];
            d3[0] = fmaf(va[0], ff[1], fmaf(va[1], ff[2], va[2] * ff[3]));
            d3[1] = fmaf(va[3], ff[1], fmaf(vb[0], ff[2], vb[1] * ff[3]));
            d3[2] = fmaf(vb[2], ff[1], fmaf(vb[3], ff[2], vc[0] * ff[3]));
            d3[3] = fmaf(vc[1], ff[1], fmaf(vc[2], ff[2], vc[3] * ff[3]));
            #pragma unroll
            for (int j = 0; j < 4; ++j) {
                float hq = s[j] * fmaf(q_in, aq[j], bqv[j]);
                float hv = fmaf(s[j], fmaf(ff[0], av[j], bvv[j]), a1[j] * d3[j]);
                hfrag[k][4 * h + j]     = (short)f2bf(hq);
                hfrag[k + 4][4 * h + j] = (short)f2bf(hv);
            }
        }

        // ---- prefetch burst A: next tile halves 0..3 + scalars ----
        const int nt = tile + gridDim.x;
        int ndn = -1;
        float c0n = 0.f, cin = 0.f; f32x4 ffn = ffr;
        if (nt < T) {
            ndn = nt * 64 + wave * 16 + nl;
            ndn = ndn < N ? ndn : N - 1;
            NLOAD_RANGE(ndn, 0, 4)
            c0n = c0[ndn]; cin = ci[ndn];
            ffn = reinterpret_cast<const f32x4*>(field)[ndn];
        }

        // ---- GEMM1 (K=256, 64 MFMA) ----
        f32x4 acc[8];
        #pragma unroll
        for (int mt = 0; mt < 8; ++mt) acc[mt] = vl4[160 + mt * 4 + g];   // b1
        #pragma unroll
        for (int ks = 0; ks < 8; ++ks) {
            #pragma unroll
            for (int mt = 0; mt < 8; ++mt) {
                short8 a = *reinterpret_cast<const short8*>(
                    smem + (mt * 8 + ks) * 1024 + lane * 16);
                acc[mt] = __builtin_amdgcn_mfma_f32_16x16x32_bf16(a, hfrag[ks], acc[mt], 0, 0, 0);
            }
        }

        // ---- prefetch burst B: next tile halves 4..7 ----
        if (ndn >= 0) {
            NLOAD_RANGE(ndn, 4, 8)
        }

        // ---- silu + store h1 (feat = mt*16 + g*4 + j, byte = 2*feat) ----
        if (nd < N) {
            char* hrow = (char*)h1 + (size_t)nd * 256 + g * 8;
            #pragma unroll
            for (int mt = 0; mt < 8; ++mt) {
                uint2v w;
                w[0] = (unsigned int)f2bf(silu(acc[mt][0])) |
                       ((unsigned int)f2bf(silu(acc[mt][1])) << 16);
                w[1] = (unsigned int)f2bf(silu(acc[mt][2])) |
                       ((unsigned int)f2bf(silu(acc[mt][3])) << 16);
                *reinterpret_cast<uint2v*>(hrow + mt * 32) = w;
            }
        }

        c0r = c0n; cir = cin; ffr = ffn;
    }
#undef NLOAD_RANGE
#undef NLOAD_SC
}

// ---------------------------------------------------------------------------
// Kernel B: h1 -> GEMM2 -> GEMM3 -> W4 dot -> out.
// 256 threads = 4 waves; LDS = W2|W3 (64KB) + consts -> 2 blocks/CU.
// Per tile only 4x16B dense h-loads per lane (double-buffered ping-pong).
// ---------------------------------------------------------------------------
__global__ __launch_bounds__(256, 1) void mlp_tail(
    const float* __restrict__ vecs,
    const unsigned short* __restrict__ wp,
    const unsigned short* __restrict__ h1,
    float* __restrict__ out, int N)
{
    __shared__ __align__(16) char smem[65536];
    __shared__ __align__(16) float vlds[1156];
    const int tid  = threadIdx.x;
    const int wave = tid >> 6;
    const int lane = tid & 63;
    const int g    = lane >> 4;
    const int nl   = lane & 15;
    const int T    = (N + 63) >> 6;
    const char* wpb = (const char*)wp;
    const char* h1b = (const char*)h1;

    // ---- stage W2|W3 (64KB, wp bytes [64K,128K)) into LDS ----
    #pragma unroll
    for (int i = 0; i < 16; ++i) {
        int off = (wave * 16 + i) * 1024;
        __builtin_amdgcn_global_load_lds((gchar*)(wpb + 65536 + off + lane * 16),
                                         (schar*)(smem + off), 16, 0, 0);
    }
    if (wave == 0) {
        #pragma unroll
        for (int i = 0; i < 5; ++i) {
            int idx = lane + 64 * i;
            if (idx < 289)
                reinterpret_cast<f32x4*>(vlds)[idx] =
                    reinterpret_cast<const f32x4*>(vecs)[idx];
        }
    }

    const f32x4* vl4 = reinterpret_cast<const f32x4*>(vlds);

#define H_LOAD(arr, ndx) {                                                    \
        const char* hb_ = h1b + (size_t)(ndx) * 256 + g * 16;                 \
        _Pragma("unroll")                                                     \
        for (int ks_ = 0; ks_ < 4; ++ks_)                                     \
            arr[ks_] = *reinterpret_cast<const short8*>(hb_ + ks_ * 64); }

#define TAIL_COMPUTE(tile_, harr) {                                           \
        const int nd_ = (tile_) * 64 + wave * 16 + nl;                        \
        f32x4 acc2[8];                                                        \
        _Pragma("unroll")                                                     \
        for (int mt = 0; mt < 8; ++mt) acc2[mt] = vl4[192 + mt * 4 + g];      \
        _Pragma("unroll")                                                     \
        for (int ks = 0; ks < 4; ++ks) {                                      \
            _Pragma("unroll")                                                 \
            for (int mt = 0; mt < 8; ++mt) {                                  \
                short8 a = *reinterpret_cast<const short8*>(                  \
                    smem + (mt * 4 + ks) * 1024 + lane * 16);                 \
                acc2[mt] = __builtin_amdgcn_mfma_f32_16x16x32_bf16(a, harr[ks], acc2[mt], 0, 0, 0); \
            }                                                                 \
        }                                                                     \
        short8 hf3[4];                                                        \
        _Pragma("unroll")                                                     \
        for (int ks = 0; ks < 4; ++ks)                                        \
            _Pragma("unroll")                                                 \
            for (int hp = 0; hp < 2; ++hp)                                    \
                _Pragma("unroll")                                             \
                for (int j = 0; j < 4; ++j)                                   \
                    hf3[ks][hp * 4 + j] = (short)f2bf(silu(acc2[hp * 4 + ks][j])); \
        f32x4 acc3[8];                                                        \
        _Pragma("unroll")                                                     \
        for (int mt = 0; mt < 8; ++mt) acc3[mt] = vl4[224 + mt * 4 + g];      \
        _Pragma("unroll")                                                     \
        for (int ks = 0; ks < 4; ++ks) {                                      \
            _Pragma("unroll")                                                 \
            for (int mt = 0; mt < 8; ++mt) {                                  \
                short8 a = *reinterpret_cast<const short8*>(                  \
                    smem + 32768 + (mt * 4 + ks) * 1024 + lane * 16);         \
                acc3[mt] = __builtin_amdgcn_mfma_f32_16x16x32_bf16(a, hf3[ks], acc3[mt], 0, 0, 0); \
            }                                                                 \
        }                                                                     \
        float acc_out = 0.f;                                                  \
        _Pragma("unroll")                                                     \
        for (int mt = 0; mt < 8; ++mt) {                                      \
            f32x4 w4v = vl4[256 + mt * 4 + g];                                \
            acc_out += silu(acc3[mt][0]) * w4v[0];                            \
            acc_out += silu(acc3[mt][1]) * w4v[1];                            \
            acc_out += silu(acc3[mt][2]) * w4v[2];                            \
            acc_out += silu(acc3[mt][3]) * w4v[3];                            \
        }                                                                     \
        acc_out += __shfl_xor(acc_out, 16, 64);                               \
        acc_out += __shfl_xor(acc_out, 32, 64);                               \
        if (g == 0 && nd_ < N) out[nd_] = acc_out + vlds[1152]; }

    short8 hA[4], hB[4];
    int tile = blockIdx.x;
    {
        int nd0 = tile * 64 + wave * 16 + nl;
        int ndc = nd0 < N ? nd0 : N - 1;
        H_LOAD(hA, ndc)
    }

    __syncthreads();   // W2|W3 + consts resident

    bool done = false;
    while (!done) {
        {   // iteration with cur=hA, prefetch->hB
            int nt = tile + gridDim.x;
            if (nt < T) {
                int ndn = nt * 64 + wave * 16 + nl;
                ndn = ndn < N ? ndn : N - 1;
                H_LOAD(hB, ndn)
            }
            TAIL_COMPUTE(tile, hA)
            if (nt >= T) { done = true; } else { tile = nt; }
        }
        if (done) break;
        {   // iteration with cur=hB, prefetch->hA
            int nt = tile + gridDim.x;
            if (nt < T) {
                int ndn = nt * 64 + wave * 16 + nl;
                ndn = ndn < N ? ndn : N - 1;
                H_LOAD(hA, ndn)
            }
            TAIL_COMPUTE(tile, hB)
            if (nt >= T) { done = true; } else { tile = nt; }
        }
    }
#undef H_LOAD
#undef TAIL_COMPUTE
}

extern "C" void kernel_launch(void* const* d_in, const int* in_sizes, int n_in,
                              void* d_out, int out_size, void* d_ws, size_t ws_size,
                              hipStream_t stream) {
    const float* node_feats = (const float*)d_in[1];
    const float* field      = (const float*)d_in[5];
    const float* c0         = (const float*)d_in[6];
    const float* ci         = (const float*)d_in[7];
    const float* Wq0        = (const float*)d_in[8];
    const float* bq         = (const float*)d_in[9];
    const float* Wv0        = (const float*)d_in[10];
    const float* bv         = (const float*)d_in[11];
    const float* Wv1        = (const float*)d_in[12];
    const float* wq_s       = (const float*)d_in[13];
    // d_in[14] = wq_v multiplies q_up_v == 0 -> unused
    const float* wv_s       = (const float*)d_in[15];
    const float* wv_v       = (const float*)d_in[16];
    const float* W1         = (const float*)d_in[17];
    const float* b1         = (const float*)d_in[18];
    const float* W2         = (const float*)d_in[19];
    const float* b2         = (const float*)d_in[20];
    const float* W3         = (const float*)d_in[21];
    const float* b3         = (const float*)d_in[22];
    const float* W4         = (const float*)d_in[23];
    const float* b4         = (const float*)d_in[24];

    const int N = in_sizes[1] / 512;           // node_feats is [N, 4*C]
    float* vecs = (float*)d_ws;                                   // 8KB
    unsigned short* wp = (unsigned short*)((char*)d_ws + 8192);   // 128KB
    unsigned short* h1 = (unsigned short*)((char*)d_ws + 139264); // N*256B

    prep_all<<<129, 128, 0, stream>>>(Wq0, bq, Wv0, bv, Wv1, wq_s, wv_s, wv_v,
                                      W1, W2, W3, b1, b2, b3, W4, b4, vecs, wp);
    const int T = (N + 63) / 64;
    const int blocksA = T < 512 ? T : 512;
    gemm1_fused<<<blocksA, 256, 0, stream>>>(node_feats, field, c0, ci, vecs, wp,
                                             h1, N);
    const int blocksB = T < 512 ? T : 512;
    mlp_tail<<<blocksB, 256, 0, stream>>>(vecs, wp, h1, (float*)d_out, N);
}

// Round 14
// 104.375 us; speedup vs baseline: 1.9843x; 1.9843x over previous
//
#include <hip/hip_runtime.h>
#include <hip/hip_bf16.h>

typedef __attribute__((ext_vector_type(8))) short short8;
typedef __attribute__((ext_vector_type(4))) float f32x4;
typedef __attribute__((ext_vector_type(2))) unsigned int uint2v;

#define PATH_W 0.0625f
#define INV_SQRT3 0.57735026918962576f

typedef const __attribute__((address_space(1))) char gchar;
typedef __attribute__((address_space(3))) char schar;

__device__ __forceinline__ unsigned short f2bf(float f) {
    unsigned int u = __builtin_bit_cast(unsigned int, f);
    u += 0x7FFFu + ((u >> 16) & 1u);   // round-to-nearest-even
    return (unsigned short)(u >> 16);
}

__device__ __forceinline__ float silu(float x) {
    return x / (1.0f + __expf(-x));
}

// ---------------------------------------------------------------------------
// Prep: block 0 -> coefficient/constant table (pre-scaled coeffs + biases).
// Blocks 1..128 -> frag-major bf16 weight fragments:
//   W1 (fid 0..63)  STANDARD pack: k = ks*32 + g*8 + half*4 + j
//   W2 (fid 64..95) STANDARD pack (B-frags come from h1 memory in standard
//                   layout, so A must match)
//   W3 (fid 96..127) PHI pack: k = half*64 + ks*16 + g*4 + j (matches GEMM2
//                   D-register layout -> in-register repack, no exchange)
// ---------------------------------------------------------------------------
__global__ void prep_all(const float* __restrict__ Wq0, const float* __restrict__ bq,
                         const float* __restrict__ Wv0, const float* __restrict__ bv,
                         const float* __restrict__ Wv1, const float* __restrict__ wq_s,
                         const float* __restrict__ wv_s, const float* __restrict__ wv_v,
                         const float* __restrict__ W1, const float* __restrict__ W2,
                         const float* __restrict__ W3, const float* __restrict__ b1,
                         const float* __restrict__ b2, const float* __restrict__ b3,
                         const float* __restrict__ W4, const float* __restrict__ b4,
                         float* __restrict__ vecs, unsigned short* __restrict__ wp) {
    if (blockIdx.x == 0) {
        int u = threadIdx.x;  // 0..127
        float aq = 0.f, bqs = 0.f, av = 0.f, bvs = 0.f, a1 = 0.f;
        for (int v = 0; v < 128; ++v) {
            float rq = wq_s[u * 128 + v];
            float rv = wv_s[u * 128 + v];
            aq  += Wq0[v] * rq;
            bqs += bq[v]  * rq;
            av  += Wv0[v] * rv;
            bvs += bv[v]  * rv;
            a1  += Wv1[v] * wv_v[u * 128 + v];
        }
        vecs[u]        = PATH_W * aq;
        vecs[128 + u]  = PATH_W * bqs;
        vecs[256 + u]  = PATH_W * av;
        vecs[384 + u]  = PATH_W * bvs;
        vecs[512 + u]  = PATH_W * INV_SQRT3 * a1;
        vecs[640 + u]  = b1[u];
        vecs[768 + u]  = b2[u];
        vecs[896 + u]  = b3[u];
        vecs[1024 + u] = W4[u];
        if (u == 0) { vecs[1152] = b4[0]; vecs[1153] = 0.f; vecs[1154] = 0.f; vecs[1155] = 0.f; }
        return;
    }
    int fid  = blockIdx.x - 1;      // 0..127
    int t    = threadIdx.x;         // 0..127
    int lane = t & 63;
    int half = t >> 6;
    int g  = lane >> 4;
    int r  = lane & 15;
    const float* W;
    int row0, col;
    if (fid < 64) {                       // W1: standard pack
        int mt = fid >> 3, ks = fid & 7;
        W = W1; col = mt * 16 + r;
        row0 = ks * 32 + g * 8 + half * 4;
    } else if (fid < 96) {                // W2: standard pack
        int f2 = fid - 64;
        int mt = f2 >> 2, ks = f2 & 3;
        W = W2; col = mt * 16 + r;
        row0 = ks * 32 + g * 8 + half * 4;
    } else {                              // W3: phi pack
        int f2 = fid - 96;
        int mt = f2 >> 2, ks = f2 & 3;
        W = W3; col = mt * 16 + r;
        row0 = half * 64 + ks * 16 + g * 4;
    }
    unsigned short* dst = wp + fid * 512 + lane * 8 + half * 4;
    #pragma unroll
    for (int j = 0; j < 4; ++j) dst[j] = f2bf(W[(row0 + j) * 128 + col]);
}

// ---------------------------------------------------------------------------
// Kernel A (round 14): r8's PROVEN no-spill loop (8-slot full-tile ring,
// in-place slot refill pinned by sched_barrier(0), per-quarter hfA/hfB
// consumption) with the GEMM2/3 tail replaced by the h1 store.
// LDS = W1 (64KB) + consts -> TWO de-phased blocks/CU (the TLP r8 lacked).
// ---------------------------------------------------------------------------
__global__ __launch_bounds__(256, 1) void gemm1_fused(
    const float* __restrict__ nf,     // node_feats [N,512]
    const float* __restrict__ field,  // field_feats [N,4]
    const float* __restrict__ c0, const float* __restrict__ ci,
    const float* __restrict__ vecs,   // constant table (1156 f32)
    const unsigned short* __restrict__ wp,
    unsigned short* __restrict__ h1,  // out: [N][128] bf16
    int N)
{
    __shared__ __align__(16) char smem[65536];
    __shared__ __align__(16) float vlds[1156];
    const int tid  = threadIdx.x;
    const int wave = tid >> 6;      // 0..3
    const int lane = tid & 63;
    const int g    = lane >> 4;
    const int nl   = lane & 15;
    const int T    = (N + 63) >> 6;
    const char* wpb = (const char*)wp;

    // ---- stage W1 (64KB) into LDS once (16KB per wave) ----
    #pragma unroll
    for (int i = 0; i < 16; ++i) {
        int off = (wave * 16 + i) * 1024;
        __builtin_amdgcn_global_load_lds((gchar*)(wpb + off + lane * 16),
                                         (schar*)(smem + off), 16, 0, 0);
    }
    if (wave == 0) {
        #pragma unroll
        for (int i = 0; i < 5; ++i) {
            int idx = lane + 64 * i;
            if (idx < 289)
                reinterpret_cast<f32x4*>(vlds)[idx] =
                    reinterpret_cast<const f32x4*>(vecs)[idx];
        }
    }

    // full-tile ring: 8 slots x (s 16B + v 48B) = 512B/lane = 128 VGPRs
    f32x4 hs[8], hv0[8], hv1[8], hv2[8];
    float c0r, cir; f32x4 ffr;
    const char* bsr; const char* bvr;

#define SLOT_LOAD(hh_, bs_, bv_) {                                            \
        const int q_ = (hh_) >> 1, h_ = (hh_) & 1;                            \
        hs[hh_]  = *reinterpret_cast<const f32x4*>((bs_) + 128 * q_ + 16 * h_); \
        hv0[hh_] = *reinterpret_cast<const f32x4*>((bv_) + 384 * q_ + 48 * h_); \
        hv1[hh_] = *reinterpret_cast<const f32x4*>((bv_) + 384 * q_ + 48 * h_ + 16); \
        hv2[hh_] = *reinterpret_cast<const f32x4*>((bv_) + 384 * q_ + 48 * h_ + 32); }

    int tile = blockIdx.x;
    {   // prologue: load full tile 0 + scalars
        int nd0 = tile * 64 + wave * 16 + nl;
        int ndc = nd0 < N ? nd0 : N - 1;
        const char* nrow = (const char*)nf + (size_t)ndc * 2048;
        bsr = nrow + 32 * g;
        bvr = nrow + 512 + 96 * g;
        #pragma unroll
        for (int hh = 0; hh < 8; ++hh) SLOT_LOAD(hh, bsr, bvr)
        c0r = c0[ndc]; cir = ci[ndc];
        ffr = reinterpret_cast<const f32x4*>(field)[ndc];
    }

    __syncthreads();   // W1 + consts resident

    const f32x4* vl4 = reinterpret_cast<const f32x4*>(vlds);

    for (; tile < T; tile += gridDim.x) {
        const int nd = tile * 64 + wave * 16 + nl;
        const int nt = tile + gridDim.x;
        const bool hasnext = nt < T;

        // next-tile bases + scalar prefetch (issued first -> oldest in FIFO)
        const char* bsn = bsr; const char* bvn = bvr;
        float c0n = 0.f, cin = 0.f; f32x4 ffn = ffr;
        if (hasnext) {
            int ndn = nt * 64 + wave * 16 + nl;
            ndn = ndn < N ? ndn : N - 1;
            const char* nrow = (const char*)nf + (size_t)ndn * 2048;
            bsn = nrow + 32 * g;
            bvn = nrow + 512 + 96 * g;
            c0n = c0[ndn]; cin = ci[ndn];
            ffn = reinterpret_cast<const f32x4*>(field)[ndn];
        }

        const float q_in = c0r + cir;
        const f32x4 ff   = ffr;

        // ---- GEMM1 (K=256): per-quarter h-compute + MFMA, in-place refill ----
        f32x4 acc[8];
        #pragma unroll
        for (int mt = 0; mt < 8; ++mt) acc[mt] = vl4[160 + mt * 4 + g];   // b1

        short8 hfA, hfB;
        #pragma unroll
        for (int q = 0; q < 4; ++q) {
            #pragma unroll
            for (int h = 0; h < 2; ++h) {
                const int hh = 2 * q + h;
                const int m  = 8 * q + 2 * g + h;
                f32x4 aq = vl4[m], bqv = vl4[32 + m], av = vl4[64 + m],
                      bvv = vl4[96 + m], a1 = vl4[128 + m];
                f32x4 s = hs[hh], va = hv0[hh], vb = hv1[hh], vc = hv2[hh];
                float d3[4];
                d3[0] = fmaf(va[0], ff[1], fmaf(va[1], ff[2], va[2] * ff[3]));
                d3[1] = fmaf(va[3], ff[1], fmaf(vb[0], ff[2], vb[1] * ff[3]));
                d3[2] = fmaf(vb[2], ff[1], fmaf(vb[3], ff[2], vc[0] * ff[3]));
                d3[3] = fmaf(vc[1], ff[1], fmaf(vc[2], ff[2], vc[3] * ff[3]));
                #pragma unroll
                for (int j = 0; j < 4; ++j) {
                    float hq = s[j] * fmaf(q_in, aq[j], bqv[j]);
                    float hv = fmaf(s[j], fmaf(ff[0], av[j], bvv[j]), a1[j] * d3[j]);
                    if (h == 0) { hfA[j]     = (short)f2bf(hq); hfB[j]     = (short)f2bf(hv); }
                    else        { hfA[4 + j] = (short)f2bf(hq); hfB[4 + j] = (short)f2bf(hv); }
                }
                // pin: slot hh fully consumed above; refill may not hoist past
                __builtin_amdgcn_sched_barrier(0);
                if (hasnext) SLOT_LOAD(hh, bsn, bvn)
            }
            // quarter q complete: 16 MFMA (ks=q with hfA, ks=q+4 with hfB)
            #pragma unroll
            for (int mt = 0; mt < 8; ++mt) {
                short8 a0 = *reinterpret_cast<const short8*>(
                    smem + (mt * 8 + q) * 1024 + lane * 16);
                acc[mt] = __builtin_amdgcn_mfma_f32_16x16x32_bf16(a0, hfA, acc[mt], 0, 0, 0);
                short8 a4 = *reinterpret_cast<const short8*>(
                    smem + (mt * 8 + q + 4) * 1024 + lane * 16);
                acc[mt] = __builtin_amdgcn_mfma_f32_16x16x32_bf16(a4, hfB, acc[mt], 0, 0, 0);
            }
        }

        // ---- silu + store h1 (feat = mt*16 + g*4 + j, byte = 2*feat) ----
        if (nd < N) {
            char* hrow = (char*)h1 + (size_t)nd * 256 + g * 8;
            #pragma unroll
            for (int mt = 0; mt < 8; ++mt) {
                uint2v w;
                w[0] = (unsigned int)f2bf(silu(acc[mt][0])) |
                       ((unsigned int)f2bf(silu(acc[mt][1])) << 16);
                w[1] = (unsigned int)f2bf(silu(acc[mt][2])) |
                       ((unsigned int)f2bf(silu(acc[mt][3])) << 16);
                *reinterpret_cast<uint2v*>(hrow + mt * 32) = w;
            }
        }

        // advance to next tile
        bsr = bsn; bvr = bvn;
        c0r = c0n; cir = cin; ffr = ffn;
    }
#undef SLOT_LOAD
}

// ---------------------------------------------------------------------------
// Kernel B: h1 -> GEMM2 -> GEMM3 -> W4 dot -> out.   (unchanged from r13)
// 256 threads = 4 waves; LDS = W2|W3 (64KB) + consts -> 2 blocks/CU.
// ---------------------------------------------------------------------------
__global__ __launch_bounds__(256, 1) void mlp_tail(
    const float* __restrict__ vecs,
    const unsigned short* __restrict__ wp,
    const unsigned short* __restrict__ h1,
    float* __restrict__ out, int N)
{
    __shared__ __align__(16) char smem[65536];
    __shared__ __align__(16) float vlds[1156];
    const int tid  = threadIdx.x;
    const int wave = tid >> 6;
    const int lane = tid & 63;
    const int g    = lane >> 4;
    const int nl   = lane & 15;
    const int T    = (N + 63) >> 6;
    const char* wpb = (const char*)wp;
    const char* h1b = (const char*)h1;

    // ---- stage W2|W3 (64KB, wp bytes [64K,128K)) into LDS ----
    #pragma unroll
    for (int i = 0; i < 16; ++i) {
        int off = (wave * 16 + i) * 1024;
        __builtin_amdgcn_global_load_lds((gchar*)(wpb + 65536 + off + lane * 16),
                                         (schar*)(smem + off), 16, 0, 0);
    }
    if (wave == 0) {
        #pragma unroll
        for (int i = 0; i < 5; ++i) {
            int idx = lane + 64 * i;
            if (idx < 289)
                reinterpret_cast<f32x4*>(vlds)[idx] =
                    reinterpret_cast<const f32x4*>(vecs)[idx];
        }
    }

    const f32x4* vl4 = reinterpret_cast<const f32x4*>(vlds);

#define H_LOAD(arr, ndx) {                                                    \
        const char* hb_ = h1b + (size_t)(ndx) * 256 + g * 16;                 \
        _Pragma("unroll")                                                     \
        for (int ks_ = 0; ks_ < 4; ++ks_)                                     \
            arr[ks_] = *reinterpret_cast<const short8*>(hb_ + ks_ * 64); }

#define TAIL_COMPUTE(tile_, harr) {                                           \
        const int nd_ = (tile_) * 64 + wave * 16 + nl;                        \
        f32x4 acc2[8];                                                        \
        _Pragma("unroll")                                                     \
        for (int mt = 0; mt < 8; ++mt) acc2[mt] = vl4[192 + mt * 4 + g];      \
        _Pragma("unroll")                                                     \
        for (int ks = 0; ks < 4; ++ks) {                                      \
            _Pragma("unroll")                                                 \
            for (int mt = 0; mt < 8; ++mt) {                                  \
                short8 a = *reinterpret_cast<const short8*>(                  \
                    smem + (mt * 4 + ks) * 1024 + lane * 16);                 \
                acc2[mt] = __builtin_amdgcn_mfma_f32_16x16x32_bf16(a, harr[ks], acc2[mt], 0, 0, 0); \
            }                                                                 \
        }                                                                     \
        short8 hf3[4];                                                        \
        _Pragma("unroll")                                                     \
        for (int ks = 0; ks < 4; ++ks)                                        \
            _Pragma("unroll")                                                 \
            for (int hp = 0; hp < 2; ++hp)                                    \
                _Pragma("unroll")                                             \
                for (int j = 0; j < 4; ++j)                                   \
                    hf3[ks][hp * 4 + j] = (short)f2bf(silu(acc2[hp * 4 + ks][j])); \
        f32x4 acc3[8];                                                        \
        _Pragma("unroll")                                                     \
        for (int mt = 0; mt < 8; ++mt) acc3[mt] = vl4[224 + mt * 4 + g];      \
        _Pragma("unroll")                                                     \
        for (int ks = 0; ks < 4; ++ks) {                                      \
            _Pragma("unroll")                                                 \
            for (int mt = 0; mt < 8; ++mt) {                                  \
                short8 a = *reinterpret_cast<const short8*>(                  \
                    smem + 32768 + (mt * 4 + ks) * 1024 + lane * 16);         \
                acc3[mt] = __builtin_amdgcn_mfma_f32_16x16x32_bf16(a, hf3[ks], acc3[mt], 0, 0, 0); \
            }                                                                 \
        }                                                                     \
        float acc_out = 0.f;                                                  \
        _Pragma("unroll")                                                     \
        for (int mt = 0; mt < 8; ++mt) {                                      \
            f32x4 w4v = vl4[256 + mt * 4 + g];                                \
            acc_out += silu(acc3[mt][0]) * w4v[0];                            \
            acc_out += silu(acc3[mt][1]) * w4v[1];                            \
            acc_out += silu(acc3[mt][2]) * w4v[2];                            \
            acc_out += silu(acc3[mt][3]) * w4v[3];                            \
        }                                                                     \
        acc_out += __shfl_xor(acc_out, 16, 64);                               \
        acc_out += __shfl_xor(acc_out, 32, 64);                               \
        if (g == 0 && nd_ < N) out[nd_] = acc_out + vlds[1152]; }

    short8 hA[4], hB[4];
    int tile = blockIdx.x;
    {
        int nd0 = tile * 64 + wave * 16 + nl;
        int ndc = nd0 < N ? nd0 : N - 1;
        H_LOAD(hA, ndc)
    }

    __syncthreads();   // W2|W3 + consts resident

    bool done = false;
    while (!done) {
        {   // iteration with cur=hA, prefetch->hB
            int nt = tile + gridDim.x;
            if (nt < T) {
                int ndn = nt * 64 + wave * 16 + nl;
                ndn = ndn < N ? ndn : N - 1;
                H_LOAD(hB, ndn)
            }
            TAIL_COMPUTE(tile, hA)
            if (nt >= T) { done = true; } else { tile = nt; }
        }
        if (done) break;
        {   // iteration with cur=hB, prefetch->hA
            int nt = tile + gridDim.x;
            if (nt < T) {
                int ndn = nt * 64 + wave * 16 + nl;
                ndn = ndn < N ? ndn : N - 1;
                H_LOAD(hA, ndn)
            }
            TAIL_COMPUTE(tile, hB)
            if (nt >= T) { done = true; } else { tile = nt; }
        }
    }
#undef H_LOAD
#undef TAIL_COMPUTE
}

extern "C" void kernel_launch(void* const* d_in, const int* in_sizes, int n_in,
                              void* d_out, int out_size, void* d_ws, size_t ws_size,
                              hipStream_t stream) {
    const float* node_feats = (const float*)d_in[1];
    const float* field      = (const float*)d_in[5];
    const float* c0         = (const float*)d_in[6];
    const float* ci         = (const float*)d_in[7];
    const float* Wq0        = (const float*)d_in[8];
    const float* bq         = (const float*)d_in[9];
    const float* Wv0        = (const float*)d_in[10];
    const float* bv         = (const float*)d_in[11];
    const float* Wv1        = (const float*)d_in[12];
    const float* wq_s       = (const float*)d_in[13];
    // d_in[14] = wq_v multiplies q_up_v == 0 -> unused
    const float* wv_s       = (const float*)d_in[15];
    const float* wv_v       = (const float*)d_in[16];
    const float* W1         = (const float*)d_in[17];
    const float* b1         = (const float*)d_in[18];
    const float* W2         = (const float*)d_in[19];
    const float* b2         = (const float*)d_in[20];
    const float* W3         = (const float*)d_in[21];
    const float* b3         = (const float*)d_in[22];
    const float* W4         = (const float*)d_in[23];
    const float* b4         = (const float*)d_in[24];

    const int N = in_sizes[1] / 512;           // node_feats is [N, 4*C]
    float* vecs = (float*)d_ws;                                   // 8KB
    unsigned short* wp = (unsigned short*)((char*)d_ws + 8192);   // 128KB
    unsigned short* h1 = (unsigned short*)((char*)d_ws + 139264); // N*256B

    prep_all<<<129, 128, 0, stream>>>(Wq0, bq, Wv0, bv, Wv1, wq_s, wv_s, wv_v,
                                      W1, W2, W3, b1, b2, b3, W4, b4, vecs, wp);
    const int T = (N + 63) / 64;
    const int blocksA = T < 512 ? T : 512;
    gemm1_fused<<<blocksA, 256, 0, stream>>>(node_feats, field, c0, ci, vecs, wp,
                                             h1, N);
    const int blocksB = T < 512 ? T : 512;
    mlp_tail<<<blocksB, 256, 0, stream>>>(vecs, wp, h1, (float*)d_out, N);
}

// Round 15
// 91.344 us; speedup vs baseline: 2.2674x; 1.1427x over previous
//
#include <hip/hip_runtime.h>
#include <hip/hip_bf16.h>

typedef __attribute__((ext_vector_type(8))) short short8;
typedef __attribute__((ext_vector_type(4))) float f32x4;
typedef __attribute__((ext_vector_type(2))) unsigned int uint2v;

#define PATH_W 0.0625f
#define INV_SQRT3 0.57735026918962576f

typedef const __attribute__((address_space(1))) char gchar;
typedef __attribute__((address_space(3))) char schar;

__device__ __forceinline__ unsigned short f2bf(float f) {
    unsigned int u = __builtin_bit_cast(unsigned int, f);
    u += 0x7FFFu + ((u >> 16) & 1u);   // round-to-nearest-even
    return (unsigned short)(u >> 16);
}

__device__ __forceinline__ float silu(float x) {
    return x / (1.0f + __expf(-x));
}

// ---------------------------------------------------------------------------
// Prep: block 0 -> coefficient/constant table (pre-scaled coeffs + biases).
// Blocks 1..128 -> frag-major bf16 weight fragments:
//   W1 (fid 0..63)  STANDARD pack: k = ks*32 + g*8 + half*4 + j
//   W2 (fid 64..95) STANDARD pack (B-frags come from h1 memory)
//   W3 (fid 96..127) PHI pack: k = half*64 + ks*16 + g*4 + j
// ---------------------------------------------------------------------------
__global__ void prep_all(const float* __restrict__ Wq0, const float* __restrict__ bq,
                         const float* __restrict__ Wv0, const float* __restrict__ bv,
                         const float* __restrict__ Wv1, const float* __restrict__ wq_s,
                         const float* __restrict__ wv_s, const float* __restrict__ wv_v,
                         const float* __restrict__ W1, const float* __restrict__ W2,
                         const float* __restrict__ W3, const float* __restrict__ b1,
                         const float* __restrict__ b2, const float* __restrict__ b3,
                         const float* __restrict__ W4, const float* __restrict__ b4,
                         float* __restrict__ vecs, unsigned short* __restrict__ wp) {
    if (blockIdx.x == 0) {
        int u = threadIdx.x;  // 0..127
        float aq = 0.f, bqs = 0.f, av = 0.f, bvs = 0.f, a1 = 0.f;
        for (int v = 0; v < 128; ++v) {
            float rq = wq_s[u * 128 + v];
            float rv = wv_s[u * 128 + v];
            aq  += Wq0[v] * rq;
            bqs += bq[v]  * rq;
            av  += Wv0[v] * rv;
            bvs += bv[v]  * rv;
            a1  += Wv1[v] * wv_v[u * 128 + v];
        }
        vecs[u]        = PATH_W * aq;
        vecs[128 + u]  = PATH_W * bqs;
        vecs[256 + u]  = PATH_W * av;
        vecs[384 + u]  = PATH_W * bvs;
        vecs[512 + u]  = PATH_W * INV_SQRT3 * a1;
        vecs[640 + u]  = b1[u];
        vecs[768 + u]  = b2[u];
        vecs[896 + u]  = b3[u];
        vecs[1024 + u] = W4[u];
        if (u == 0) { vecs[1152] = b4[0]; vecs[1153] = 0.f; vecs[1154] = 0.f; vecs[1155] = 0.f; }
        return;
    }
    int fid  = blockIdx.x - 1;      // 0..127
    int t    = threadIdx.x;         // 0..127
    int lane = t & 63;
    int half = t >> 6;
    int g  = lane >> 4;
    int r  = lane & 15;
    const float* W;
    int row0, col;
    if (fid < 64) {                       // W1: standard pack
        int mt = fid >> 3, ks = fid & 7;
        W = W1; col = mt * 16 + r;
        row0 = ks * 32 + g * 8 + half * 4;
    } else if (fid < 96) {                // W2: standard pack
        int f2 = fid - 64;
        int mt = f2 >> 2, ks = f2 & 3;
        W = W2; col = mt * 16 + r;
        row0 = ks * 32 + g * 8 + half * 4;
    } else {                              // W3: phi pack
        int f2 = fid - 96;
        int mt = f2 >> 2, ks = f2 & 3;
        W = W3; col = mt * 16 + r;
        row0 = half * 64 + ks * 16 + g * 4;
    }
    unsigned short* dst = wp + fid * 512 + lane * 8 + half * 4;
    #pragma unroll
    for (int j = 0; j < 4; ++j) dst[j] = f2bf(W[(row0 + j) * 128 + col]);
}

// ---------------------------------------------------------------------------
// Kernel A (round 15): r10's proven 2-slot-ring loop (in-place refill pinned
// by sched_barrier, per-quarter hfA/hfB consumption -- fits the 128-VGPR cap
// of a 512-thread block with NO spill) with the GEMM2/3 tail replaced by the
// h1 store and LDS cut to W1-only (69KB) -> TWO blocks/CU = 16 waves/CU
// (4/SIMD), double r10's TLP. De-phased blocks hide waitcnt/VALU latency.
// ---------------------------------------------------------------------------
__global__ __launch_bounds__(512, 2) void gemm1_fused(
    const float* __restrict__ nf,     // node_feats [N,512]
    const float* __restrict__ field,  // field_feats [N,4]
    const float* __restrict__ c0, const float* __restrict__ ci,
    const float* __restrict__ vecs,   // constant table (1156 f32)
    const unsigned short* __restrict__ wp,
    unsigned short* __restrict__ h1,  // out: [N][128] bf16
    int N)
{
    __shared__ __align__(16) char smem[65536];
    __shared__ __align__(16) float vlds[1156];
    const int tid  = threadIdx.x;
    const int wave = tid >> 6;      // 0..7
    const int lane = tid & 63;
    const int g    = lane >> 4;
    const int nl   = lane & 15;
    const int T    = (N + 127) >> 7;   // 128-node tiles
    const char* wpb = (const char*)wp;

    // ---- stage W1 (64KB) into LDS once (8KB per wave) ----
    #pragma unroll
    for (int i = 0; i < 8; ++i) {
        int off = (wave * 8 + i) * 1024;
        __builtin_amdgcn_global_load_lds((gchar*)(wpb + off + lane * 16),
                                         (schar*)(smem + off), 16, 0, 0);
    }
    if (wave == 0) {
        #pragma unroll
        for (int i = 0; i < 5; ++i) {
            int idx = lane + 64 * i;
            if (idx < 289)
                reinterpret_cast<f32x4*>(vlds)[idx] =
                    reinterpret_cast<const f32x4*>(vecs)[idx];
        }
    }

    // 2-slot ring: 2 x (s 16B + v 48B) = 128B/lane = 32 VGPRs
    f32x4 hs[2], hv0[2], hv1[2], hv2[2];
    float c0r, cir; f32x4 ffr;
    const char* bsr; const char* bvr;   // current-tile bases

#define SLOT_LOAD(sl_, q_, h_, bs_, bv_) {                                    \
        hs[sl_]  = *reinterpret_cast<const f32x4*>((bs_) + 128 * (q_) + 16 * (h_)); \
        hv0[sl_] = *reinterpret_cast<const f32x4*>((bv_) + 384 * (q_) + 48 * (h_)); \
        hv1[sl_] = *reinterpret_cast<const f32x4*>((bv_) + 384 * (q_) + 48 * (h_) + 16); \
        hv2[sl_] = *reinterpret_cast<const f32x4*>((bv_) + 384 * (q_) + 48 * (h_) + 32); }

    int tile = blockIdx.x;
    {   // prologue: load phases 0,1 of tile 0 + scalars
        int nd0 = tile * 128 + wave * 16 + nl;
        int ndc = nd0 < N ? nd0 : N - 1;
        const char* nrow = (const char*)nf + (size_t)ndc * 2048;
        bsr = nrow + 32 * g;
        bvr = nrow + 512 + 96 * g;
        c0r = c0[ndc]; cir = ci[ndc];
        ffr = reinterpret_cast<const f32x4*>(field)[ndc];
        SLOT_LOAD(0, 0, 0, bsr, bvr)
        SLOT_LOAD(1, 0, 1, bsr, bvr)
    }

    __syncthreads();   // W1 + consts resident

    const f32x4* vl4 = reinterpret_cast<const f32x4*>(vlds);

    for (; tile < T; tile += gridDim.x) {
        const int nd = tile * 128 + wave * 16 + nl;
        const int nt = tile + gridDim.x;
        const bool hasnext = nt < T;

        // next-tile bases + scalar prefetch
        const char* bsn = bsr; const char* bvn = bvr;
        float c0n = 0.f, cin = 0.f; f32x4 ffn = ffr;
        if (hasnext) {
            int ndn = nt * 128 + wave * 16 + nl;
            ndn = ndn < N ? ndn : N - 1;
            const char* nrow = (const char*)nf + (size_t)ndn * 2048;
            bsn = nrow + 32 * g;
            bvn = nrow + 512 + 96 * g;
            c0n = c0[ndn]; cin = ci[ndn];
            ffn = reinterpret_cast<const f32x4*>(field)[ndn];
        }

        const float q_in = c0r + cir;
        const f32x4 ff   = ffr;

        // ---- GEMM1 (K=256): 8 phases, 2-slot ring, in-place refill ----
        f32x4 acc[8];
        #pragma unroll
        for (int mt = 0; mt < 8; ++mt) acc[mt] = vl4[160 + mt * 4 + g];   // b1

        short8 hfA, hfB;
        #pragma unroll
        for (int q = 0; q < 4; ++q) {
            #pragma unroll
            for (int h = 0; h < 2; ++h) {
                const int p = 2 * q + h;
                const int slot = p & 1;
                const int m = 8 * q + 2 * g + h;
                f32x4 aq = vl4[m], bqv = vl4[32 + m], av = vl4[64 + m],
                      bvv = vl4[96 + m], a1 = vl4[128 + m];
                f32x4 s = hs[slot], va = hv0[slot], vb = hv1[slot], vc = hv2[slot];
                float d3[4];
                d3[0] = fmaf(va[0], ff[1], fmaf(va[1], ff[2], va[2] * ff[3]));
                d3[1] = fmaf(va[3], ff[1], fmaf(vb[0], ff[2], vb[1] * ff[3]));
                d3[2] = fmaf(vb[2], ff[1], fmaf(vb[3], ff[2], vc[0] * ff[3]));
                d3[3] = fmaf(vc[1], ff[1], fmaf(vc[2], ff[2], vc[3] * ff[3]));
                #pragma unroll
                for (int j = 0; j < 4; ++j) {
                    float hq = s[j] * fmaf(q_in, aq[j], bqv[j]);
                    float hv = fmaf(s[j], fmaf(ff[0], av[j], bvv[j]), a1[j] * d3[j]);
                    if (h == 0) { hfA[j]     = (short)f2bf(hq); hfB[j]     = (short)f2bf(hv); }
                    else        { hfA[4 + j] = (short)f2bf(hq); hfB[4 + j] = (short)f2bf(hv); }
                }
                // pin: slot consumed above; refill must not hoist past this
                __builtin_amdgcn_sched_barrier(0);
                if (p < 6) {
                    const int pn = p + 2;
                    SLOT_LOAD(slot, pn >> 1, pn & 1, bsr, bvr)     // current tile
                } else if (hasnext) {
                    SLOT_LOAD(slot, 0, p - 6, bsn, bvn)            // next tile ph 0/1
                }
            }
            // quarter q complete: 16 MFMA (ks=q with hfA, ks=q+4 with hfB)
            #pragma unroll
            for (int mt = 0; mt < 8; ++mt) {
                short8 a0 = *reinterpret_cast<const short8*>(
                    smem + (mt * 8 + q) * 1024 + lane * 16);
                acc[mt] = __builtin_amdgcn_mfma_f32_16x16x32_bf16(a0, hfA, acc[mt], 0, 0, 0);
                short8 a4 = *reinterpret_cast<const short8*>(
                    smem + (mt * 8 + q + 4) * 1024 + lane * 16);
                acc[mt] = __builtin_amdgcn_mfma_f32_16x16x32_bf16(a4, hfB, acc[mt], 0, 0, 0);
            }
        }

        // ---- silu + store h1 (feat = mt*16 + g*4 + j, byte = 2*feat) ----
        if (nd < N) {
            char* hrow = (char*)h1 + (size_t)nd * 256 + g * 8;
            #pragma unroll
            for (int mt = 0; mt < 8; ++mt) {
                uint2v w;
                w[0] = (unsigned int)f2bf(silu(acc[mt][0])) |
                       ((unsigned int)f2bf(silu(acc[mt][1])) << 16);
                w[1] = (unsigned int)f2bf(silu(acc[mt][2])) |
                       ((unsigned int)f2bf(silu(acc[mt][3])) << 16);
                *reinterpret_cast<uint2v*>(hrow + mt * 32) = w;
            }
        }

        // advance to next tile
        bsr = bsn; bvr = bvn;
        c0r = c0n; cir = cin; ffr = ffn;
    }
#undef SLOT_LOAD
}

// ---------------------------------------------------------------------------
// Kernel B: h1 -> GEMM2 -> GEMM3 -> W4 dot -> out.  (r14, unchanged)
// 256 threads = 4 waves; LDS = W2|W3 (64KB) + consts -> 2 blocks/CU.
// ---------------------------------------------------------------------------
__global__ __launch_bounds__(256, 1) void mlp_tail(
    const float* __restrict__ vecs,
    const unsigned short* __restrict__ wp,
    const unsigned short* __restrict__ h1,
    float* __restrict__ out, int N)
{
    __shared__ __align__(16) char smem[65536];
    __shared__ __align__(16) float vlds[1156];
    const int tid  = threadIdx.x;
    const int wave = tid >> 6;
    const int lane = tid & 63;
    const int g    = lane >> 4;
    const int nl   = lane & 15;
    const int T    = (N + 63) >> 6;
    const char* wpb = (const char*)wp;
    const char* h1b = (const char*)h1;

    // ---- stage W2|W3 (64KB, wp bytes [64K,128K)) into LDS ----
    #pragma unroll
    for (int i = 0; i < 16; ++i) {
        int off = (wave * 16 + i) * 1024;
        __builtin_amdgcn_global_load_lds((gchar*)(wpb + 65536 + off + lane * 16),
                                         (schar*)(smem + off), 16, 0, 0);
    }
    if (wave == 0) {
        #pragma unroll
        for (int i = 0; i < 5; ++i) {
            int idx = lane + 64 * i;
            if (idx < 289)
                reinterpret_cast<f32x4*>(vlds)[idx] =
                    reinterpret_cast<const f32x4*>(vecs)[idx];
        }
    }

    const f32x4* vl4 = reinterpret_cast<const f32x4*>(vlds);

#define H_LOAD(arr, ndx) {                                                    \
        const char* hb_ = h1b + (size_t)(ndx) * 256 + g * 16;                 \
        _Pragma("unroll")                                                     \
        for (int ks_ = 0; ks_ < 4; ++ks_)                                     \
            arr[ks_] = *reinterpret_cast<const short8*>(hb_ + ks_ * 64); }

#define TAIL_COMPUTE(tile_, harr) {                                           \
        const int nd_ = (tile_) * 64 + wave * 16 + nl;                        \
        f32x4 acc2[8];                                                        \
        _Pragma("unroll")                                                     \
        for (int mt = 0; mt < 8; ++mt) acc2[mt] = vl4[192 + mt * 4 + g];      \
        _Pragma("unroll")                                                     \
        for (int ks = 0; ks < 4; ++ks) {                                      \
            _Pragma("unroll")                                                 \
            for (int mt = 0; mt < 8; ++mt) {                                  \
                short8 a = *reinterpret_cast<const short8*>(                  \
                    smem + (mt * 4 + ks) * 1024 + lane * 16);                 \
                acc2[mt] = __builtin_amdgcn_mfma_f32_16x16x32_bf16(a, harr[ks], acc2[mt], 0, 0, 0); \
            }                                                                 \
        }                                                                     \
        short8 hf3[4];                                                        \
        _Pragma("unroll")                                                     \
        for (int ks = 0; ks < 4; ++ks)                                        \
            _Pragma("unroll")                                                 \
            for (int hp = 0; hp < 2; ++hp)                                    \
                _Pragma("unroll")                                             \
                for (int j = 0; j < 4; ++j)                                   \
                    hf3[ks][hp * 4 + j] = (short)f2bf(silu(acc2[hp * 4 + ks][j])); \
        f32x4 acc3[8];                                                        \
        _Pragma("unroll")                                                     \
        for (int mt = 0; mt < 8; ++mt) acc3[mt] = vl4[224 + mt * 4 + g];      \
        _Pragma("unroll")                                                     \
        for (int ks = 0; ks < 4; ++ks) {                                      \
            _Pragma("unroll")                                                 \
            for (int mt = 0; mt < 8; ++mt) {                                  \
                short8 a = *reinterpret_cast<const short8*>(                  \
                    smem + 32768 + (mt * 4 + ks) * 1024 + lane * 16);         \
                acc3[mt] = __builtin_amdgcn_mfma_f32_16x16x32_bf16(a, hf3[ks], acc3[mt], 0, 0, 0); \
            }                                                                 \
        }                                                                     \
        float acc_out = 0.f;                                                  \
        _Pragma("unroll")                                                     \
        for (int mt = 0; mt < 8; ++mt) {                                      \
            f32x4 w4v = vl4[256 + mt * 4 + g];                                \
            acc_out += silu(acc3[mt][0]) * w4v[0];                            \
            acc_out += silu(acc3[mt][1]) * w4v[1];                            \
            acc_out += silu(acc3[mt][2]) * w4v[2];                            \
            acc_out += silu(acc3[mt][3]) * w4v[3];                            \
        }                                                                     \
        acc_out += __shfl_xor(acc_out, 16, 64);                               \
        acc_out += __shfl_xor(acc_out, 32, 64);                               \
        if (g == 0 && nd_ < N) out[nd_] = acc_out + vlds[1152]; }

    short8 hA[4], hB[4];
    int tile = blockIdx.x;
    {
        int nd0 = tile * 64 + wave * 16 + nl;
        int ndc = nd0 < N ? nd0 : N - 1;
        H_LOAD(hA, ndc)
    }

    __syncthreads();   // W2|W3 + consts resident

    bool done = false;
    while (!done) {
        {   // iteration with cur=hA, prefetch->hB
            int nt = tile + gridDim.x;
            if (nt < T) {
                int ndn = nt * 64 + wave * 16 + nl;
                ndn = ndn < N ? ndn : N - 1;
                H_LOAD(hB, ndn)
            }
            TAIL_COMPUTE(tile, hA)
            if (nt >= T) { done = true; } else { tile = nt; }
        }
        if (done) break;
        {   // iteration with cur=hB, prefetch->hA
            int nt = tile + gridDim.x;
            if (nt < T) {
                int ndn = nt * 64 + wave * 16 + nl;
                ndn = ndn < N ? ndn : N - 1;
                H_LOAD(hA, ndn)
            }
            TAIL_COMPUTE(tile, hB)
            if (nt >= T) { done = true; } else { tile = nt; }
        }
    }
#undef H_LOAD
#undef TAIL_COMPUTE
}

extern "C" void kernel_launch(void* const* d_in, const int* in_sizes, int n_in,
                              void* d_out, int out_size, void* d_ws, size_t ws_size,
                              hipStream_t stream) {
    const float* node_feats = (const float*)d_in[1];
    const float* field      = (const float*)d_in[5];
    const float* c0         = (const float*)d_in[6];
    const float* ci         = (const float*)d_in[7];
    const float* Wq0        = (const float*)d_in[8];
    const float* bq         = (const float*)d_in[9];
    const float* Wv0        = (const float*)d_in[10];
    const float* bv         = (const float*)d_in[11];
    const float* Wv1        = (const float*)d_in[12];
    const float* wq_s       = (const float*)d_in[13];
    // d_in[14] = wq_v multiplies q_up_v == 0 -> unused
    const float* wv_s       = (const float*)d_in[15];
    const float* wv_v       = (const float*)d_in[16];
    const float* W1         = (const float*)d_in[17];
    const float* b1         = (const float*)d_in[18];
    const float* W2         = (const float*)d_in[19];
    const float* b2         = (const float*)d_in[20];
    const float* W3         = (const float*)d_in[21];
    const float* b3         = (const float*)d_in[22];
    const float* W4         = (const float*)d_in[23];
    const float* b4         = (const float*)d_in[24];

    const int N = in_sizes[1] / 512;           // node_feats is [N, 4*C]
    float* vecs = (float*)d_ws;                                   // 8KB
    unsigned short* wp = (unsigned short*)((char*)d_ws + 8192);   // 128KB
    unsigned short* h1 = (unsigned short*)((char*)d_ws + 139264); // N*256B

    prep_all<<<129, 128, 0, stream>>>(Wq0, bq, Wv0, bv, Wv1, wq_s, wv_s, wv_v,
                                      W1, W2, W3, b1, b2, b3, W4, b4, vecs, wp);
    const int T128 = (N + 127) / 128;
    const int blocksA = T128 < 512 ? T128 : 512;
    gemm1_fused<<<blocksA, 512, 0, stream>>>(node_feats, field, c0, ci, vecs, wp,
                                             h1, N);
    const int T64 = (N + 63) / 64;
    const int blocksB = T64 < 512 ? T64 : 512;
    mlp_tail<<<blocksB, 256, 0, stream>>>(vecs, wp, h1, (float*)d_out, N);
}

// Round 16
// 90.783 us; speedup vs baseline: 2.2814x; 1.0062x over previous
//
#include <hip/hip_runtime.h>
#include <hip/hip_bf16.h>

typedef __attribute__((ext_vector_type(8))) short short8;
typedef __attribute__((ext_vector_type(4))) float f32x4;
typedef __attribute__((ext_vector_type(2))) unsigned int uint2v;

#define PATH_W 0.0625f
#define INV_SQRT3 0.57735026918962576f

typedef const __attribute__((address_space(1))) char gchar;
typedef __attribute__((address_space(3))) char schar;

__device__ __forceinline__ unsigned short f2bf(float f) {
    unsigned int u = __builtin_bit_cast(unsigned int, f);
    u += 0x7FFFu + ((u >> 16) & 1u);   // round-to-nearest-even
    return (unsigned short)(u >> 16);
}

__device__ __forceinline__ float silu(float x) {
    return x / (1.0f + __expf(-x));
}

// ---------------------------------------------------------------------------
// Prep (r15, unchanged): block 0 -> constant table; blocks 1..128 -> frag-major
// bf16 weights: W1 standard, W2 standard, W3 phi-pack.
// ---------------------------------------------------------------------------
__global__ void prep_all(const float* __restrict__ Wq0, const float* __restrict__ bq,
                         const float* __restrict__ Wv0, const float* __restrict__ bv,
                         const float* __restrict__ Wv1, const float* __restrict__ wq_s,
                         const float* __restrict__ wv_s, const float* __restrict__ wv_v,
                         const float* __restrict__ W1, const float* __restrict__ W2,
                         const float* __restrict__ W3, const float* __restrict__ b1,
                         const float* __restrict__ b2, const float* __restrict__ b3,
                         const float* __restrict__ W4, const float* __restrict__ b4,
                         float* __restrict__ vecs, unsigned short* __restrict__ wp) {
    if (blockIdx.x == 0) {
        int u = threadIdx.x;  // 0..127
        float aq = 0.f, bqs = 0.f, av = 0.f, bvs = 0.f, a1 = 0.f;
        for (int v = 0; v < 128; ++v) {
            float rq = wq_s[u * 128 + v];
            float rv = wv_s[u * 128 + v];
            aq  += Wq0[v] * rq;
            bqs += bq[v]  * rq;
            av  += Wv0[v] * rv;
            bvs += bv[v]  * rv;
            a1  += Wv1[v] * wv_v[u * 128 + v];
        }
        vecs[u]        = PATH_W * aq;
        vecs[128 + u]  = PATH_W * bqs;
        vecs[256 + u]  = PATH_W * av;
        vecs[384 + u]  = PATH_W * bvs;
        vecs[512 + u]  = PATH_W * INV_SQRT3 * a1;
        vecs[640 + u]  = b1[u];
        vecs[768 + u]  = b2[u];
        vecs[896 + u]  = b3[u];
        vecs[1024 + u] = W4[u];
        if (u == 0) { vecs[1152] = b4[0]; vecs[1153] = 0.f; vecs[1154] = 0.f; vecs[1155] = 0.f; }
        return;
    }
    int fid  = blockIdx.x - 1;      // 0..127
    int t    = threadIdx.x;         // 0..127
    int lane = t & 63;
    int half = t >> 6;
    int g  = lane >> 4;
    int r  = lane & 15;
    const float* W;
    int row0, col;
    if (fid < 64) {                       // W1: standard pack
        int mt = fid >> 3, ks = fid & 7;
        W = W1; col = mt * 16 + r;
        row0 = ks * 32 + g * 8 + half * 4;
    } else if (fid < 96) {                // W2: standard pack
        int f2 = fid - 64;
        int mt = f2 >> 2, ks = f2 & 3;
        W = W2; col = mt * 16 + r;
        row0 = ks * 32 + g * 8 + half * 4;
    } else {                              // W3: phi pack
        int f2 = fid - 96;
        int mt = f2 >> 2, ks = f2 & 3;
        W = W3; col = mt * 16 + r;
        row0 = half * 64 + ks * 16 + g * 4;
    }
    unsigned short* dst = wp + fid * 512 + lane * 8 + half * 4;
    #pragma unroll
    for (int j = 0; j < 4; ++j) dst[j] = f2bf(W[(row0 + j) * 128 + col]);
}

// ---------------------------------------------------------------------------
// Kernel A (round 16): cooperative staged GEMM1. 512 thr = 8 waves, 1 block/CU.
// LDS: W1 64K | stage buf0 32K | buf1 32K | hbuf0 8K | hbuf1 8K (+consts).
// Per 16-node microtile: coalesced global_load_lds staging (source
// pre-swizzled by node for conflict-free LDS reads), counted vmcnt(7) + raw
// s_barrier (prefetch of the NEXT microtile stays in flight across barriers
// -- never vmcnt(0) in the loop), cooperative h-compute into MFMA-layout
// bf16 B-frags, then each wave MFMAs one mt output slice (acc = 4 VGPRs).
// In-flight depth = 32KB/CU LDS buffer (not VGPR-bound, not wave-bound).
// ---------------------------------------------------------------------------
__global__ __launch_bounds__(512, 1) void gemm1_coop(
    const float* __restrict__ nf,     // node_feats [N,512]
    const float* __restrict__ field,  // field_feats [N,4]
    const float* __restrict__ c0, const float* __restrict__ ci,
    const float* __restrict__ vecs,   // constant table (1156 f32)
    const unsigned short* __restrict__ wp,
    unsigned short* __restrict__ h1,  // out: [N][128] bf16
    int N)
{
    __shared__ __align__(16) char smem[147456];
    __shared__ __align__(16) float vlds[1156];
    const int tid  = threadIdx.x;
    const int wave = tid >> 6;      // 0..7  (== mt slice this wave computes)
    const int lane = tid & 63;
    const int g    = lane >> 4;     // 0..3
    const int n    = lane & 15;     // node-in-microtile == MFMA column
    const int T    = (N + 15) >> 4; // 16-node microtiles
    const char* wpb = (const char*)wp;
    const char* nfb = (const char*)nf;

    // ---- stage W1 (64KB) into LDS (8KB per wave), async ----
    #pragma unroll
    for (int i = 0; i < 8; ++i) {
        int off = (wave * 8 + i) * 1024;
        __builtin_amdgcn_global_load_lds((gchar*)(wpb + off + lane * 16),
                                         (schar*)(smem + off), 16, 0, 0);
    }
    // ---- constant table -> LDS (wave 0); writer drains its LDS writes ----
    if (wave == 0) {
        #pragma unroll
        for (int i = 0; i < 5; ++i) {
            int idx = lane + 64 * i;
            if (idx < 289)
                reinterpret_cast<f32x4*>(vlds)[idx] =
                    reinterpret_cast<const f32x4*>(vecs)[idx];
        }
        asm volatile("s_waitcnt lgkmcnt(0)" ::: "memory");
    }

    // STAGE: microtile it -> buf b. 4 instrs/thread, each wave-instr = 1KB
    // coalesced (source chunk-permuted within 128B lines by node for the
    // conflict-free read swizzle; line set unchanged -> coalescing intact).
#define STAGE(b_, it_) {                                                      \
        _Pragma("unroll")                                                     \
        for (int j_ = 0; j_ < 4; ++j_) {                                      \
            int slot = (wave * 4 + j_) * 64 + lane;   /* 0..2047 */           \
            int sn = slot >> 7;                        /* node 0..15 */       \
            int sc = slot & 127;                       /* chunk 0..127 */     \
            int gn = (it_) * 16 + sn; gn = gn < N ? gn : N - 1;               \
            __builtin_amdgcn_global_load_lds(                                 \
                (gchar*)(nfb + (size_t)gn * 2048 + ((sc ^ (sn & 7)) << 4)),   \
                (schar*)(smem + 65536 + (b_) * 32768 + (wave * 4 + j_) * 1024), \
                16, 0, 0);                                                    \
        } }

    int it = blockIdx.x;
    int cur = 0;
    float c0r, cir; f32x4 ffr;
    {   // prologue: stage microtile 0 + its scalars (7 vmem ops)
        STAGE(0, it)
        int gn = it * 16 + n; gn = gn < N ? gn : N - 1;
        ffr = reinterpret_cast<const f32x4*>(field)[gn];
        c0r = c0[gn]; cir = ci[gn];
    }

    const f32x4* vl4 = reinterpret_cast<const f32x4*>(vlds);
    const int cb = wave * 4 + (lane >> 4);   // channel-block 0..31 (producer)
    const int sw = n & 7;                    // read-side swizzle
    const int pks = cb >> 3;                 // producer frag ks (0..3)
    const int pg  = (cb >> 1) & 3;           // producer frag g
    const int ph  = cb & 1;                  // producer frag half

    for (; it < T; it += gridDim.x) {
        const int nx = it + gridDim.x;
        const bool hasnext = nx < T;

        float c0n = 0.f, cin = 0.f; f32x4 ffn = ffr;
        if (hasnext) {
            STAGE(cur ^ 1, nx)
            int gn = nx * 16 + n; gn = gn < N ? gn : N - 1;
            ffn = reinterpret_cast<const f32x4*>(field)[gn];
            c0n = c0[gn]; cin = ci[gn];
            // the 7 newest vmem ops are exactly next-tile stage+scalars:
            asm volatile("s_waitcnt vmcnt(7)" ::: "memory");
        } else {
            asm volatile("s_waitcnt vmcnt(0)" ::: "memory");
        }
        __builtin_amdgcn_sched_barrier(0);
        __builtin_amdgcn_s_barrier();      // stage cur complete, all waves
        __builtin_amdgcn_sched_barrier(0);

        // ---- cooperative h-compute: 4 channels/thread -> hbuf[cur] ----
        {
            const char* B = smem + 65536 + cur * 32768 + n * 2048;
            f32x4 s  = *reinterpret_cast<const f32x4*>(B + ((cb            ^ sw) << 4));
            f32x4 va = *reinterpret_cast<const f32x4*>(B + (((32 + 3 * cb)     ^ sw) << 4));
            f32x4 vb = *reinterpret_cast<const f32x4*>(B + (((32 + 3 * cb + 1) ^ sw) << 4));
            f32x4 vc = *reinterpret_cast<const f32x4*>(B + (((32 + 3 * cb + 2) ^ sw) << 4));
            f32x4 aq = vl4[cb], bqv = vl4[32 + cb], av = vl4[64 + cb],
                  bvv = vl4[96 + cb], a1 = vl4[128 + cb];
            const float q_in = c0r + cir;
            const f32x4 ff   = ffr;
            float d3[4];
            d3[0] = fmaf(va[0], ff[1], fmaf(va[1], ff[2], va[2] * ff[3]));
            d3[1] = fmaf(va[3], ff[1], fmaf(vb[0], ff[2], vb[1] * ff[3]));
            d3[2] = fmaf(vb[2], ff[1], fmaf(vb[3], ff[2], vc[0] * ff[3]));
            d3[3] = fmaf(vc[1], ff[1], fmaf(vc[2], ff[2], vc[3] * ff[3]));
            unsigned int q0, q1, v0, v1;
            {
                float hq0 = s[0] * fmaf(q_in, aq[0], bqv[0]);
                float hq1 = s[1] * fmaf(q_in, aq[1], bqv[1]);
                float hq2 = s[2] * fmaf(q_in, aq[2], bqv[2]);
                float hq3 = s[3] * fmaf(q_in, aq[3], bqv[3]);
                q0 = (unsigned int)f2bf(hq0) | ((unsigned int)f2bf(hq1) << 16);
                q1 = (unsigned int)f2bf(hq2) | ((unsigned int)f2bf(hq3) << 16);
                float hv0 = fmaf(s[0], fmaf(ff[0], av[0], bvv[0]), a1[0] * d3[0]);
                float hv1 = fmaf(s[1], fmaf(ff[0], av[1], bvv[1]), a1[1] * d3[1]);
                float hv2 = fmaf(s[2], fmaf(ff[0], av[2], bvv[2]), a1[2] * d3[2]);
                float hv3 = fmaf(s[3], fmaf(ff[0], av[3], bvv[3]), a1[3] * d3[3]);
                v0 = (unsigned int)f2bf(hv0) | ((unsigned int)f2bf(hv1) << 16);
                v1 = (unsigned int)f2bf(hv2) | ((unsigned int)f2bf(hv3) << 16);
            }
            char* HB = smem + 131072 + cur * 8192;
            uint2v wq; wq[0] = q0; wq[1] = q1;
            uint2v wv; wv[0] = v0; wv[1] = v1;
            *reinterpret_cast<uint2v*>(HB + pks * 1024 + pg * 256 + n * 16 + ph * 8) = wq;
            *reinterpret_cast<uint2v*>(HB + (pks + 4) * 1024 + pg * 256 + n * 16 + ph * 8) = wv;
        }
        asm volatile("s_waitcnt lgkmcnt(0)" ::: "memory");
        __builtin_amdgcn_sched_barrier(0);
        __builtin_amdgcn_s_barrier();      // hbuf[cur] ready
        __builtin_amdgcn_sched_barrier(0);

        // ---- GEMM1 slice: wave = mt, acc = 4 VGPRs (K=256, 8 MFMA) ----
        {
            f32x4 acc = vl4[160 + wave * 4 + g];   // b1 slice
            const char* HB = smem + 131072 + cur * 8192;
            #pragma unroll
            for (int ks = 0; ks < 8; ++ks) {
                short8 bfr = *reinterpret_cast<const short8*>(HB + ks * 1024 + lane * 16);
                short8 afr = *reinterpret_cast<const short8*>(
                    smem + (wave * 8 + ks) * 1024 + lane * 16);
                acc = __builtin_amdgcn_mfma_f32_16x16x32_bf16(afr, bfr, acc, 0, 0, 0);
            }
            const int nd = it * 16 + n;
            if (nd < N) {
                uint2v w;
                w[0] = (unsigned int)f2bf(silu(acc[0])) |
                       ((unsigned int)f2bf(silu(acc[1])) << 16);
                w[1] = (unsigned int)f2bf(silu(acc[2])) |
                       ((unsigned int)f2bf(silu(acc[3])) << 16);
                *reinterpret_cast<uint2v*>(
                    (char*)h1 + (size_t)nd * 256 + (wave * 16 + g * 4) * 2) = w;
            }
        }

        cur ^= 1;
        c0r = c0n; cir = cin; ffr = ffn;
    }
#undef STAGE
}

// ---------------------------------------------------------------------------
// Kernel B: h1 -> GEMM2 -> GEMM3 -> W4 dot -> out.  (r14/r15, unchanged)
// ---------------------------------------------------------------------------
__global__ __launch_bounds__(256, 1) void mlp_tail(
    const float* __restrict__ vecs,
    const unsigned short* __restrict__ wp,
    const unsigned short* __restrict__ h1,
    float* __restrict__ out, int N)
{
    __shared__ __align__(16) char smem[65536];
    __shared__ __align__(16) float vlds[1156];
    const int tid  = threadIdx.x;
    const int wave = tid >> 6;
    const int lane = tid & 63;
    const int g    = lane >> 4;
    const int nl   = lane & 15;
    const int T    = (N + 63) >> 6;
    const char* wpb = (const char*)wp;
    const char* h1b = (const char*)h1;

    #pragma unroll
    for (int i = 0; i < 16; ++i) {
        int off = (wave * 16 + i) * 1024;
        __builtin_amdgcn_global_load_lds((gchar*)(wpb + 65536 + off + lane * 16),
                                         (schar*)(smem + off), 16, 0, 0);
    }
    if (wave == 0) {
        #pragma unroll
        for (int i = 0; i < 5; ++i) {
            int idx = lane + 64 * i;
            if (idx < 289)
                reinterpret_cast<f32x4*>(vlds)[idx] =
                    reinterpret_cast<const f32x4*>(vecs)[idx];
        }
    }

    const f32x4* vl4 = reinterpret_cast<const f32x4*>(vlds);

#define H_LOAD(arr, ndx) {                                                    \
        const char* hb_ = h1b + (size_t)(ndx) * 256 + g * 16;                 \
        _Pragma("unroll")                                                     \
        for (int ks_ = 0; ks_ < 4; ++ks_)                                     \
            arr[ks_] = *reinterpret_cast<const short8*>(hb_ + ks_ * 64); }

#define TAIL_COMPUTE(tile_, harr) {                                           \
        const int nd_ = (tile_) * 64 + wave * 16 + nl;                        \
        f32x4 acc2[8];                                                        \
        _Pragma("unroll")                                                     \
        for (int mt = 0; mt < 8; ++mt) acc2[mt] = vl4[192 + mt * 4 + g];      \
        _Pragma("unroll")                                                     \
        for (int ks = 0; ks < 4; ++ks) {                                      \
            _Pragma("unroll")                                                 \
            for (int mt = 0; mt < 8; ++mt) {                                  \
                short8 a = *reinterpret_cast<const short8*>(                  \
                    smem + (mt * 4 + ks) * 1024 + lane * 16);                 \
                acc2[mt] = __builtin_amdgcn_mfma_f32_16x16x32_bf16(a, harr[ks], acc2[mt], 0, 0, 0); \
            }                                                                 \
        }                                                                     \
        short8 hf3[4];                                                        \
        _Pragma("unroll")                                                     \
        for (int ks = 0; ks < 4; ++ks)                                        \
            _Pragma("unroll")                                                 \
            for (int hp = 0; hp < 2; ++hp)                                    \
                _Pragma("unroll")                                             \
                for (int j = 0; j < 4; ++j)                                   \
                    hf3[ks][hp * 4 + j] = (short)f2bf(silu(acc2[hp * 4 + ks][j])); \
        f32x4 acc3[8];                                                        \
        _Pragma("unroll")                                                     \
        for (int mt = 0; mt < 8; ++mt) acc3[mt] = vl4[224 + mt * 4 + g];      \
        _Pragma("unroll")                                                     \
        for (int ks = 0; ks < 4; ++ks) {                                      \
            _Pragma("unroll")                                                 \
            for (int mt = 0; mt < 8; ++mt) {                                  \
                short8 a = *reinterpret_cast<const short8*>(                  \
                    smem + 32768 + (mt * 4 + ks) * 1024 + lane * 16);         \
                acc3[mt] = __builtin_amdgcn_mfma_f32_16x16x32_bf16(a, hf3[ks], acc3[mt], 0, 0, 0); \
            }                                                                 \
        }                                                                     \
        float acc_out = 0.f;                                                  \
        _Pragma("unroll")                                                     \
        for (int mt = 0; mt < 8; ++mt) {                                      \
            f32x4 w4v = vl4[256 + mt * 4 + g];                                \
            acc_out += silu(acc3[mt][0]) * w4v[0];                            \
            acc_out += silu(acc3[mt][1]) * w4v[1];                            \
            acc_out += silu(acc3[mt][2]) * w4v[2];                            \
            acc_out += silu(acc3[mt][3]) * w4v[3];                            \
        }                                                                     \
        acc_out += __shfl_xor(acc_out, 16, 64);                               \
        acc_out += __shfl_xor(acc_out, 32, 64);                               \
        if (g == 0 && nd_ < N) out[nd_] = acc_out + vlds[1152]; }

    short8 hA[4], hB[4];
    int tile = blockIdx.x;
    {
        int nd0 = tile * 64 + wave * 16 + nl;
        int ndc = nd0 < N ? nd0 : N - 1;
        H_LOAD(hA, ndc)
    }

    __syncthreads();   // W2|W3 + consts resident

    bool done = false;
    while (!done) {
        {
            int nt = tile + gridDim.x;
            if (nt < T) {
                int ndn = nt * 64 + wave * 16 + nl;
                ndn = ndn < N ? ndn : N - 1;
                H_LOAD(hB, ndn)
            }
            TAIL_COMPUTE(tile, hA)
            if (nt >= T) { done = true; } else { tile = nt; }
        }
        if (done) break;
        {
            int nt = tile + gridDim.x;
            if (nt < T) {
                int ndn = nt * 64 + wave * 16 + nl;
                ndn = ndn < N ? ndn : N - 1;
                H_LOAD(hA, ndn)
            }
            TAIL_COMPUTE(tile, hB)
            if (nt >= T) { done = true; } else { tile = nt; }
        }
    }
#undef H_LOAD
#undef TAIL_COMPUTE
}

extern "C" void kernel_launch(void* const* d_in, const int* in_sizes, int n_in,
                              void* d_out, int out_size, void* d_ws, size_t ws_size,
                              hipStream_t stream) {
    const float* node_feats = (const float*)d_in[1];
    const float* field      = (const float*)d_in[5];
    const float* c0         = (const float*)d_in[6];
    const float* ci         = (const float*)d_in[7];
    const float* Wq0        = (const float*)d_in[8];
    const float* bq         = (const float*)d_in[9];
    const float* Wv0        = (const float*)d_in[10];
    const float* bv         = (const float*)d_in[11];
    const float* Wv1        = (const float*)d_in[12];
    const float* wq_s       = (const float*)d_in[13];
    // d_in[14] = wq_v multiplies q_up_v == 0 -> unused
    const float* wv_s       = (const float*)d_in[15];
    const float* wv_v       = (const float*)d_in[16];
    const float* W1         = (const float*)d_in[17];
    const float* b1         = (const float*)d_in[18];
    const float* W2         = (const float*)d_in[19];
    const float* b2         = (const float*)d_in[20];
    const float* W3         = (const float*)d_in[21];
    const float* b3         = (const float*)d_in[22];
    const float* W4         = (const float*)d_in[23];
    const float* b4         = (const float*)d_in[24];

    const int N = in_sizes[1] / 512;           // node_feats is [N, 4*C]
    float* vecs = (float*)d_ws;                                   // 8KB
    unsigned short* wp = (unsigned short*)((char*)d_ws + 8192);   // 128KB
    unsigned short* h1 = (unsigned short*)((char*)d_ws + 139264); // N*256B

    prep_all<<<129, 128, 0, stream>>>(Wq0, bq, Wv0, bv, Wv1, wq_s, wv_s, wv_v,
                                      W1, W2, W3, b1, b2, b3, W4, b4, vecs, wp);
    const int T16 = (N + 15) / 16;
    const int blocksA = T16 < 256 ? T16 : 256;
    gemm1_coop<<<blocksA, 512, 0, stream>>>(node_feats, field, c0, ci, vecs, wp,
                                            h1, N);
    const int T64 = (N + 63) / 64;
    const int blocksB = T64 < 512 ? T64 : 512;
    mlp_tail<<<blocksB, 256, 0, stream>>>(vecs, wp, h1, (float*)d_out, N);
}